// Round 6
// baseline (418.796 us; speedup 1.0000x reference)
//
#include <hip/hip_runtime.h>
#include <cfloat>
#include <cstddef>

// VQ-VAE vector quantizer, MI355X / gfx950.
// z: (32, 64, 32, 32) f32 BCHW; embedding: (1024, 64) f32.
// Outputs concatenated f32: loss[1], z_q(BCHW)[2097152], perplexity[1],
// min_encodings[32768*1024], min_encoding_indices(as float)[32768].
//
// Argmin: emulate the reference's fp32 rounding (NOT exact math):
//   d_j = fl32( fl32(z2 + e2_j) - 2*dot_j )  at magnitude ~64,
// z2/e2 double-accumulated, rounded once to fp32; dot via fp32 fma chains
// (error ~1e-9 << ulp(64) grid that dominates the comparison); first-index
// tie-break matches np.argmin. Bit-exact (absmax 0.0) rounds 2/3/5.
//
// R6: R5 showed VGPR_Count=40 despite the asm pin -> the 64-float z-row
// lives in AGPRs with v_accvgpr_read companions (2.1x VALU issue vs the
// 27us FMA floor). Fix: SPLIT CHANNELS ACROSS HALF-WAVES. Lane r holds
// ch 0-31 of row r; lane r+32 holds ch 32-63 of the same row -> zr is 32
// floats/lane (below the allocator's AGPR-copy threshold). Per code:
// 32 FMA + one __shfl_xor(32) half-dot combine (DS pipe, commutative add
// -> both halves get the bit-identical dot).

#define NROWS      32768          // B*H*W
#define NE         1024
#define EDIM       64
#define RPB        64             // rows per block
#define NBLK       (NROWS / RPB)  // 512
#define TPB        512            // 8 waves

#define OFF_LOSS   ((size_t)0)
#define OFF_ZQ     ((size_t)1)
#define OFF_PERP   ((size_t)2097153)
#define OFF_OH     ((size_t)2097154)
#define OFF_IDX    ((size_t)35651586)

typedef float f2_t __attribute__((ext_vector_type(2)));

// ws layout (bytes): [0,4096) int hist[1024]; [4096,6144) float partial[512]

__global__ __launch_bounds__(TPB, 4) void vq_main(const float* __restrict__ z,
                                                  const float* __restrict__ emb,
                                                  int* __restrict__ hist,
                                                  float* __restrict__ partial,
                                                  float* __restrict__ out) {
    const int t    = threadIdx.x;
    const int lane = t & 63;
    const int wv   = t >> 6;          // wave id, 0..7
    const int rgrp = wv >> 2;         // row group: 0 -> rows 0-31, 1 -> 32-63
    const int wq   = wv & 3;          // code quarter scanned by this wave
    const int half = lane >> 5;       // channel half
    const int rr   = lane & 31;       // row within group
    const int r0   = blockIdx.x * RPB;
    const int row  = r0 + rgrp * 32 + rr;
    const int b    = row >> 10;       // batch (1024 rows per image)
    const int m    = row & 1023;      // h*32+w
    const int ch0  = half * 32;
    const size_t zbase = (size_t)b * 65536 + (size_t)m;

    __shared__ float s_e2[NE];
    __shared__ float s_d[8][32];
    __shared__ int   s_j[8][32];
    __shared__ int   s_idx[64];
    __shared__ float s_l[8];

    // ---- per-block ||e_j||^2 into LDS (double-accumulated, fp32-rounded) --
    for (int j = t; j < NE; j += TPB) {
        const float4* e4 = (const float4*)(emb + ((size_t)j << 6));
        double s = 0.0;
#pragma unroll
        for (int k = 0; k < 16; ++k) {
            float4 v = e4[k];
            s += (double)v.x * (double)v.x;
            s += (double)v.y * (double)v.y;
            s += (double)v.z * (double)v.z;
            s += (double)v.w * (double)v.w;
        }
        s_e2[j] = (float)s;
    }

    // ---- this lane's half z-row: 32 ch (ch0..ch0+31), stride 1024 ----
    float4 zr[8];
#pragma unroll
    for (int k = 0; k < 8; ++k) {
        float4 v;
        v.x = z[zbase + (size_t)(ch0 + 4 * k + 0) * 1024];
        v.y = z[zbase + (size_t)(ch0 + 4 * k + 1) * 1024];
        v.z = z[zbase + (size_t)(ch0 + 4 * k + 2) * 1024];
        v.w = z[zbase + (size_t)(ch0 + 4 * k + 3) * 1024];
        zr[k] = v;
    }
#pragma unroll
    for (int k = 0; k < 8; ++k) {
        asm volatile("" : "+v"(zr[k].x), "+v"(zr[k].y),
                          "+v"(zr[k].z), "+v"(zr[k].w));
    }

    // ---- ||z||^2: half-sums in double, combined (commutative-exact) ----
    double z2h = 0.0;
#pragma unroll
    for (int k = 0; k < 8; ++k) {
        z2h += (double)zr[k].x * (double)zr[k].x;
        z2h += (double)zr[k].y * (double)zr[k].y;
        z2h += (double)zr[k].z * (double)zr[k].z;
        z2h += (double)zr[k].w * (double)zr[k].w;
    }
    const double z2o = __shfl_xor(z2h, 32);
    const float  z2f = (float)(z2h + z2o);

    __syncthreads();   // s_e2 ready

    // ---- scan this wave's 256-code quarter, 2 codes per iteration ----
    const int jbase = __builtin_amdgcn_readfirstlane(wq << 8);
    float bestd = FLT_MAX;
    int   bestj = NE;
    for (int jj = 0; jj < 256; jj += 2) {
        const int ja = jbase + jj;
        const int jb = ja + 1;
        const float4* ea = (const float4*)(emb + ((size_t)ja << 6) + ch0);
        const float4* eb = (const float4*)(emb + ((size_t)jb << 6) + ch0);
        float a0 = 0.f, a1 = 0.f, a2 = 0.f, a3 = 0.f;
        float b0 = 0.f, b1 = 0.f, b2 = 0.f, b3 = 0.f;
#pragma unroll
        for (int k = 0; k < 8; ++k) {
            float4 av = ea[k];
            float4 bv = eb[k];
            a0 = fmaf(av.x, zr[k].x, a0);
            a1 = fmaf(av.y, zr[k].y, a1);
            a2 = fmaf(av.z, zr[k].z, a2);
            a3 = fmaf(av.w, zr[k].w, a3);
            b0 = fmaf(bv.x, zr[k].x, b0);
            b1 = fmaf(bv.y, zr[k].y, b1);
            b2 = fmaf(bv.z, zr[k].z, b2);
            b3 = fmaf(bv.w, zr[k].w, b3);
        }
        float pa = (a0 + a1) + (a2 + a3);      // half-dot, this half
        float pb = (b0 + b1) + (b2 + b3);
        float dota = pa + __shfl_xor(pa, 32);  // commutative -> both halves
        float dotb = pb + __shfl_xor(pb, 32);  //   get the identical fp32 dot
        float da = (z2f + s_e2[ja]) - 2.0f * dota;
        float db = (z2f + s_e2[jb]) - 2.0f * dotb;
        if (da < bestd || (da == bestd && ja < bestj)) { bestd = da; bestj = ja; }
        if (db < bestd || (db == bestd && jb < bestj)) { bestd = db; bestj = jb; }
    }

    // ---- per-wave candidates (32 rows each); 4-way merge per row ----
    if (half == 0) { s_d[wv][rr] = bestd; s_j[wv][rr] = bestj; }
    __syncthreads();
    if (t < 64) {
        const int g   = t >> 5;       // row group
        const int rr2 = t & 31;
        const int w0  = g * 4;        // waves w0..w0+3, ascending code ranges
        float bd = s_d[w0][rr2];
        int   bj = s_j[w0][rr2];
#pragma unroll
        for (int i = 1; i < 4; ++i) {
            float dw = s_d[w0 + i][rr2];
            int   jw = s_j[w0 + i][rr2];
            if (dw < bd || (dw == bd && jw < bj)) { bd = dw; bj = jw; }
        }
        s_idx[t] = bj;
        out[OFF_IDX + (size_t)(r0 + t)] = (float)bj;   // indices as float
        atomicAdd(&hist[bj], 1);
    }
    __syncthreads();

    // ---- z_q (straight-through) + loss partial (t-based, as R5) ----
    const int    ln64 = lane;
    const int    q8   = wv;
    const int    rowE = r0 + ln64;
    const int    bE   = rowE >> 10;
    const int    mE   = rowE & 1023;
    const size_t zbE  = (size_t)bE * 65536 + (size_t)mE;
    const int    jjx  = s_idx[ln64];
    const float* er   = emb + ((size_t)jjx << 6);
    float* zq = out + OFF_ZQ + (size_t)bE * 65536 + (size_t)mE;
    float lsum = 0.f;
#pragma unroll
    for (int c = q8; c < EDIM; c += 8) {
        float zc   = z[zbE + (size_t)c * 1024];     // coalesced across lanes
        float ev   = er[c];                         // gather (L2-hot)
        float diff = ev - zc;
        zq[(size_t)c * 1024] = zc + diff;           // mimic zp + (z_q - zp)
        lsum = fmaf(diff, diff, lsum);
    }
#pragma unroll
    for (int off = 32; off >= 1; off >>= 1) lsum += __shfl_down(lsum, off);
    if (lane == 0) s_l[q8] = lsum;
    __syncthreads();
    if (t == 0) {
        float l = 0.f;
#pragma unroll
        for (int w = 0; w < 8; ++w) l += s_l[w];
        partial[blockIdx.x] = l;
    }

    // ---- one-hot rows: 64 rows x 1024 cols, nontemporal f2 stores ----
    float* oh = out + OFF_OH;
    for (int mm = 0; mm < RPB; ++mm) {
        int    jr   = s_idx[mm];
        float* rowp = oh + (size_t)(r0 + mm) * 1024;
        f2_t v0 = (f2_t)(0.f);
        if ((jr >> 1) == t) v0[jr & 1] = 1.0f;
        __builtin_nontemporal_store(v0, (f2_t*)rowp + t);  // cols [2t,2t+1]
    }
}

__global__ __launch_bounds__(1024) void vq_final(const int* __restrict__ hist,
                                                 const float* __restrict__ partial,
                                                 float* __restrict__ out) {
    const int t = threadIdx.x;
    float p    = (float)hist[t] * (1.0f / 32768.0f);
    float term = p * logf(p + 1e-10f);
    float lp   = (t < NBLK) ? partial[t] : 0.f;
#pragma unroll
    for (int off = 32; off >= 1; off >>= 1) {
        term += __shfl_down(term, off);
        lp   += __shfl_down(lp, off);
    }
    __shared__ float st[16], sl[16];
    int w = t >> 6, ln = t & 63;
    if (ln == 0) { st[w] = term; sl[w] = lp; }
    __syncthreads();
    if (t == 0) {
        float s = 0.f, l = 0.f;
#pragma unroll
        for (int i = 0; i < 16; ++i) { s += st[i]; l += sl[i]; }
        out[OFF_LOSS] = 1.25f * l * (1.0f / 2097152.0f);  // (1+beta)*mean
        out[OFF_PERP] = expf(-s);
    }
}

extern "C" void kernel_launch(void* const* d_in, const int* in_sizes, int n_in,
                              void* d_out, int out_size, void* d_ws, size_t ws_size,
                              hipStream_t stream) {
    const float* z   = (const float*)d_in[0];
    const float* emb = (const float*)d_in[1];
    float* out     = (float*)d_out;
    int*   hist    = (int*)d_ws;
    float* partial = (float*)((char*)d_ws + 4096);

    hipMemsetAsync(hist, 0, 4096, stream);
    vq_main<<<NBLK, TPB, 0, stream>>>(z, emb, hist, partial, out);
    vq_final<<<1, 1024, 0, stream>>>(hist, partial, out);
}